// Round 11
// baseline (850.902 us; speedup 1.0000x reference)
//
#include <hip/hip_runtime.h>
#include <hip/hip_bf16.h>

#define NN   100000
#define EE   3200000
#define HH   32
#define BB   128
#define KMAX 96
#define LSTRIDE 97       // LDS row stride (96 is 0 mod 32 -> bank storm)
#define NBKT 256         // dst buckets
#define BSPAN 391        // ceil(NN/NBKT)
#define WSPAN 98         // csr-build window (4 windows/bucket)
#define EBLK 256         // edge-chunk blocks
#define CHUNK 12500      // EE / EBLK exactly

// ws layout (bytes), non-overlapping (~60 MB)
static constexpr size_t Q_OFF      = 0;           // N*32 bf16 = 6.4 MB
static constexpr size_t AGG_OFF    = 6400000;     // N*32 f32 = 12.8 MB
static constexpr size_t H_OFF      = 19200000;    // N*32 f32 = 12.8 MB
static constexpr size_t EPACK_OFF  = 32000000;    // EE int = 12.8 MB
static constexpr size_t SRC_OFF    = 44800000;    // EE int dense csr
static constexpr size_t OFF_OFF    = 57600000;    // (N+1) int
static constexpr size_t HIST_OFF   = 58100000;    // EBLK*NBKT int = 256 KB
static constexpr size_t START_OFF  = 58400000;    // EBLK*NBKT int = 256 KB
static constexpr size_t BBASE_OFF  = 58700000;    // (NBKT+1) int
static constexpr size_t STATS_OFF  = 58710000;    // 4 layers x 64 f32
static constexpr size_t POOLED_OFF = 58711024;    // B*32 f32
static constexpr size_t PCNT_OFF   = 58727408;    // B f32
static constexpr size_t ZERO_OFF   = STATS_OFF;
static constexpr size_t ZERO_BYTES = 17920;

// ---- K1: per-block LDS histogram of dst buckets
__global__ __launch_bounds__(256) void hist_kernel(const int* __restrict__ ei,
                                                   int* __restrict__ hist) {
    __shared__ int lh[NBKT];
    int tid = threadIdx.x, blk = blockIdx.x;
    for (int i = tid; i < NBKT; i += 256) lh[i] = 0;
    __syncthreads();
    int e0 = blk * CHUNK;
    for (int e = e0 + tid; e < e0 + CHUNK; e += 256) {
        int d = ei[EE + e];
        atomicAdd(&lh[d / BSPAN], 1);
    }
    __syncthreads();
    for (int i = tid; i < NBKT; i += 256) hist[blk * NBKT + i] = lh[i];
}

// ---- K2 (fused totals+scan+starts): 1 block, thread t owns bucket t
__global__ __launch_bounds__(NBKT) void bucket_scan_kernel(const int* __restrict__ hist,
                                                           int* __restrict__ bbase,
                                                           int* __restrict__ start) {
    __shared__ int sm[NBKT];
    int t = threadIdx.x;
    int mine = 0;
    for (int blk = 0; blk < EBLK; blk++) mine += hist[blk * NBKT + t];
    sm[t] = mine;
    __syncthreads();
    for (int off = 1; off < NBKT; off <<= 1) {
        int v = (t >= off) ? sm[t - off] : 0;
        __syncthreads();
        sm[t] += v;
        __syncthreads();
    }
    int base = sm[t] - mine;   // exclusive
    bbase[t] = base;
    if (t == NBKT - 1) bbase[NBKT] = sm[t];
    int run = base;
    for (int blk = 0; blk < EBLK; blk++) {
        start[blk * NBKT + t] = run;
        run += hist[blk * NBKT + t];
    }
}

// ---- K3: scatter packed (src | dstoff<<17) into bucket-grouped array
__global__ __launch_bounds__(256) void scatter_kernel(const int* __restrict__ ei,
                                                      const int* __restrict__ start,
                                                      int* __restrict__ epack) {
    __shared__ int loff[NBKT];
    int tid = threadIdx.x, blk = blockIdx.x;
    for (int i = tid; i < NBKT; i += 256) loff[i] = start[blk * NBKT + i];
    __syncthreads();
    int e0 = blk * CHUNK;
    for (int e = e0 + tid; e < e0 + CHUNK; e += 256) {
        int s = ei[e];
        int d = ei[EE + e];
        int b = d / BSPAN;
        int slot = atomicAdd(&loff[b], 1);
        epack[slot] = s | ((d - b * BSPAN) << 17);
    }
}

// ---- K4: compact CSR build + per-node src-sort (insertion, LDS stride-97).
// Sorted lists make the gather a loosely-synchronized src sweep: at loop
// position i all resident nodes read q rows near the i/deg quantile -> the
// hot window (~1-3 MB) fits per-XCD L2 instead of thrashing the full 6.4 MB.
__global__ __launch_bounds__(256) void csr_compact_kernel(const int* __restrict__ epack,
                                                          const int* __restrict__ bbase,
                                                          int* __restrict__ off,
                                                          int* __restrict__ srcs) {
    __shared__ int lcnt[WSPAN];
    __shared__ int lbase[WSPAN + 1];
    __shared__ int lcsr[WSPAN * LSTRIDE];   // 98*97*4 = 38024 B
    __shared__ int sh_before;
    int blk = blockIdx.x;
    int b = blk >> 2, w = blk & 3;
    int base = b * BSPAN;
    int span = NN - base;
    if (span <= 0) return;
    if (span > BSPAN) span = BSPAN;
    int wstart = w * WSPAN;
    if (wstart >= span) return;
    int wend = min(wstart + WSPAN, span);
    int wn = wend - wstart;
    int tid = threadIdx.x;
    if (tid == 0) sh_before = 0;
    for (int i = tid; i < wn; i += 256) lcnt[i] = 0;
    __syncthreads();
    int p0 = bbase[b], p1 = bbase[b + 1];
    int nbefore = 0;
    for (int i = p0 + tid; i < p1; i += 256) {
        int wd = epack[i];
        int ld = wd >> 17;
        if (ld < wstart) nbefore++;
        else if (ld < wend) {
            int slot = atomicAdd(&lcnt[ld - wstart], 1);
            if (slot < KMAX) lcsr[(ld - wstart) * LSTRIDE + slot] = wd & 0x1FFFF;
        }
    }
    atomicAdd(&sh_before, nbefore);
    __syncthreads();
    if (tid == 0) {
        int run = 0;
        for (int i = 0; i < wn; i++) { lbase[i] = run; run += min(lcnt[i], KMAX); }
        lbase[wn] = run;
    }
    // per-node insertion sort by src (1 thread/node; rows stride 97 -> banks spread)
    for (int i = tid; i < wn; i += 256) {
        int d = min(lcnt[i], KMAX);
        int* row = lcsr + i * LSTRIDE;
        for (int a2 = 1; a2 < d; a2++) {
            int v = row[a2];
            int bb2 = a2 - 1;
            while (bb2 >= 0 && row[bb2] > v) { row[bb2 + 1] = row[bb2]; bb2--; }
            row[bb2 + 1] = v;
        }
    }
    __syncthreads();
    int w0 = p0 + sh_before;
    for (int i = tid; i < wn; i += 256) off[base + wstart + i] = w0 + lbase[i];
    if (base + wend == NN && tid == 0) off[NN] = w0 + lbase[wn];
    int m = lbase[wn];
    for (int j = tid; j < m; j += 256) {
        int lo = 0, hi = wn - 1;
        while (lo < hi) {
            int mid = (lo + hi + 1) >> 1;
            if (lbase[mid] <= j) lo = mid; else hi = mid - 1;
        }
        srcs[w0 + j] = lcsr[lo * LSTRIDE + (j - lbase[lo])];
    }
}

__device__ __forceinline__ unsigned bf16rn(float f) {
    unsigned b = __float_as_uint(f);
    return (b + 0x7fffu + ((b >> 16) & 1u)) >> 16;   // RNE
}

__device__ __forceinline__ void acc_row(float* a, uint4 v) {
    a[0] += __uint_as_float(v.x << 16);
    a[1] += __uint_as_float(v.x & 0xffff0000u);
    a[2] += __uint_as_float(v.y << 16);
    a[3] += __uint_as_float(v.y & 0xffff0000u);
    a[4] += __uint_as_float(v.z << 16);
    a[5] += __uint_as_float(v.z & 0xffff0000u);
    a[6] += __uint_as_float(v.w << 16);
    a[7] += __uint_as_float(v.w & 0xffff0000u);
}

// ---- projection q(bf16) = BN(h) @ w1, 4-way K-split across waves (r10-proven)
template <int FIN>
__global__ __launch_bounds__(256) void proj_kernel(const float* __restrict__ hin,
                                                   const float* __restrict__ w1,
                                                   const float* __restrict__ stats_prev,
                                                   const float* __restrict__ gamma,
                                                   const float* __restrict__ beta,
                                                   uint4* __restrict__ q4) {
    constexpr int JC = FIN / 4;
    __shared__ float sa[32], sc[32];
    __shared__ float part[4 * 64 * 33];
    int tid = threadIdx.x;
    if constexpr (FIN == 32) {
        if (tid < 32) {
            float mean = stats_prev[tid] * (1.0f / NN);
            float var  = fmaxf(stats_prev[32 + tid] * (1.0f / NN) - mean * mean, 0.f);
            float av = gamma[tid] * rsqrtf(var + 1e-5f);
            sa[tid] = av;
            sc[tid] = beta[tid] - mean * av;
        }
        __syncthreads();
    }
    int wv = __builtin_amdgcn_readfirstlane(tid >> 6);
    int ln = tid & 63;
    int n = blockIdx.x * 64 + ln;
    float acc[32];
#pragma unroll
    for (int c = 0; c < 32; c++) acc[c] = 0.f;
    if (n < NN) {
        const float4* h4 = (const float4*)(hin + (size_t)n * FIN + wv * JC);
        float hv[JC];
#pragma unroll
        for (int k = 0; k < JC / 4; k++) {
            float4 v = h4[k];
            hv[4*k] = v.x; hv[4*k+1] = v.y; hv[4*k+2] = v.z; hv[4*k+3] = v.w;
        }
        if constexpr (FIN == 32) {
#pragma unroll
            for (int j = 0; j < JC; j++) hv[j] = fmaf(hv[j], sa[wv * JC + j], sc[wv * JC + j]);
        }
#pragma unroll 4
        for (int j = 0; j < JC; j++) {
            float hvj = hv[j];
            const float* wrow = w1 + (size_t)(wv * JC + j) * 32;
#pragma unroll
            for (int c = 0; c < 32; c++) acc[c] = fmaf(hvj, wrow[c], acc[c]);
        }
    }
    float* my = part + (wv * 64 + ln) * 33;
#pragma unroll
    for (int c = 0; c < 32; c++) my[c] = acc[c];
    __syncthreads();
    int node = tid >> 2, p = tid & 3;
    int n2 = blockIdx.x * 64 + node;
    if (n2 >= NN) return;
    float r[8];
#pragma unroll
    for (int k = 0; k < 8; k++) {
        int c = p * 8 + k;
        r[k] = (part[(0 * 64 + node) * 33 + c] + part[(1 * 64 + node) * 33 + c])
             + (part[(2 * 64 + node) * 33 + c] + part[(3 * 64 + node) * 33 + c]);
    }
    uint4 u;
    u.x = bf16rn(r[0]) | (bf16rn(r[1]) << 16);
    u.y = bf16rn(r[2]) | (bf16rn(r[3]) << 16);
    u.z = bf16rn(r[4]) | (bf16rn(r[5]) << 16);
    u.w = bf16rn(r[6]) | (bf16rn(r[7]) << 16);
    q4[(size_t)n2 * 4 + p] = u;
}

// ---- gather: agg[n] = q[n] + b1 + sum q[src]. 4 lanes/node x 16 B, 8-unrolled.
__global__ __launch_bounds__(256) void gather_kernel(const uint4* __restrict__ q4,
                                                     const int* __restrict__ srcs,
                                                     const int* __restrict__ off,
                                                     const float* __restrict__ b1,
                                                     float* __restrict__ agg) {
    int t = blockIdx.x * 256 + threadIdx.x;
    int n = t >> 2;
    if (n >= NN) return;
    int p = t & 3;
    float a[8];
#pragma unroll
    for (int k = 0; k < 8; k++) a[k] = b1[p * 8 + k];
    acc_row(a, q4[(size_t)n * 4 + p]);   // self term
    int o0 = off[n];
    int d = off[n + 1] - o0;
    const int* lst = srcs + o0;
    int i = 0;
    for (; i + 8 <= d; i += 8) {
        int s0 = __builtin_nontemporal_load(lst + i);
        int s1 = __builtin_nontemporal_load(lst + i + 1);
        int s2 = __builtin_nontemporal_load(lst + i + 2);
        int s3 = __builtin_nontemporal_load(lst + i + 3);
        int s4 = __builtin_nontemporal_load(lst + i + 4);
        int s5 = __builtin_nontemporal_load(lst + i + 5);
        int s6 = __builtin_nontemporal_load(lst + i + 6);
        int s7 = __builtin_nontemporal_load(lst + i + 7);
        uint4 v0 = q4[(size_t)s0 * 4 + p];
        uint4 v1 = q4[(size_t)s1 * 4 + p];
        uint4 v2 = q4[(size_t)s2 * 4 + p];
        uint4 v3 = q4[(size_t)s3 * 4 + p];
        uint4 v4 = q4[(size_t)s4 * 4 + p];
        uint4 v5 = q4[(size_t)s5 * 4 + p];
        uint4 v6 = q4[(size_t)s6 * 4 + p];
        uint4 v7 = q4[(size_t)s7 * 4 + p];
        acc_row(a, v0); acc_row(a, v1); acc_row(a, v2); acc_row(a, v3);
        acc_row(a, v4); acc_row(a, v5); acc_row(a, v6); acc_row(a, v7);
    }
    for (; i < d; i++) {
        int s = __builtin_nontemporal_load(lst + i);
        acc_row(a, q4[(size_t)s * 4 + p]);
    }
    float4* ar = (float4*)(agg + (size_t)n * 32 + p * 8);
    float4 f0, f1;
    f0.x = a[0]; f0.y = a[1]; f0.z = a[2]; f0.w = a[3];
    f1.x = a[4]; f1.y = a[5]; f1.z = a[6]; f1.w = a[7];
    ar[0] = f0; ar[1] = f1;
}

// ---- MLP tail, 64-thread blocks (1563 blocks: fixes 391-block latency starvation).
// h = relu(relu(agg)@w2 + b2); per-block LDS stats reduce -> one atomic set.
__global__ __launch_bounds__(64) void mlp_kernel(const float* __restrict__ agg,
                                                 const float* __restrict__ w2,
                                                 const float* __restrict__ b2,
                                                 float* __restrict__ r,
                                                 float* __restrict__ stats) {
    __shared__ float tile[64 * 33];
    int tid = threadIdx.x;
    int n = blockIdx.x * 64 + tid;
    float rc[32];
    if (n < NN) {
        float u[32];
        const float4* a4 = (const float4*)(agg + (size_t)n * 32);
#pragma unroll
        for (int k = 0; k < 8; k++) {
            float4 v = a4[k];
            u[4*k]   = fmaxf(v.x, 0.f);
            u[4*k+1] = fmaxf(v.y, 0.f);
            u[4*k+2] = fmaxf(v.z, 0.f);
            u[4*k+3] = fmaxf(v.w, 0.f);
        }
#pragma unroll
        for (int c = 0; c < 32; c++) rc[c] = b2[c];
#pragma unroll 4
        for (int j = 0; j < 32; j++) {
            float uj = u[j];
            const float* wrow = w2 + (size_t)j * 32;
#pragma unroll
            for (int c = 0; c < 32; c++) rc[c] = fmaf(uj, wrow[c], rc[c]);
        }
#pragma unroll
        for (int c = 0; c < 32; c++) rc[c] = fmaxf(rc[c], 0.f);
        float4* rr = (float4*)(r + (size_t)n * 32);
#pragma unroll
        for (int k = 0; k < 8; k++) {
            float4 v; v.x = rc[4*k]; v.y = rc[4*k+1]; v.z = rc[4*k+2]; v.w = rc[4*k+3];
            rr[k] = v;
        }
    } else {
#pragma unroll
        for (int c = 0; c < 32; c++) rc[c] = 0.f;
    }
#pragma unroll
    for (int c = 0; c < 32; c++) tile[tid * 33 + c] = rc[c];
    __syncthreads();
    if (tid < 32) {
        float s = 0.f, sq = 0.f;
        for (int rr2 = 0; rr2 < 64; rr2++) {
            float v = tile[rr2 * 33 + tid];
            s += v; sq += v * v;
        }
        atomicAdd(&stats[tid], s);
        atomicAdd(&stats[32 + tid], sq);
    }
}

// ---- pooling: segment sums of raw h3 (sorted batch -> run-length flush)
#define PR 16
__global__ __launch_bounds__(256) void pool_kernel(const float* __restrict__ h,
                                                   const int* __restrict__ batch,
                                                   float* __restrict__ pooled,
                                                   float* __restrict__ pcnt) {
    int t = blockIdx.x * 256 + threadIdx.x;
    int c = t & 31;
    int g = t >> 5;
    int r0 = g * PR;
    if (r0 >= NN) return;
    int r1 = min(r0 + PR, NN);
    int cur = batch[r0];
    float acc = 0.f, cn = 0.f;
    for (int rr = r0; rr < r1; rr++) {
        int b = batch[rr];
        if (b != cur) {
            atomicAdd(&pooled[cur * 32 + c], acc);
            if (c == 0) atomicAdd(&pcnt[cur], cn);
            acc = 0.f; cn = 0.f; cur = b;
        }
        acc += h[(size_t)rr * 32 + c];
        cn += 1.f;
    }
    atomicAdd(&pooled[cur * 32 + c], acc);
    if (c == 0) atomicAdd(&pcnt[cur], cn);
}

// ---- head: BN3 (from raw stats3) on pooled means, fc1+relu, fc2, log_softmax
__global__ __launch_bounds__(128) void head_kernel(const float* __restrict__ pooled,
                                                   const float* __restrict__ pcnt,
                                                   const float* __restrict__ stats3,
                                                   const float* __restrict__ g3,
                                                   const float* __restrict__ be3,
                                                   const float* __restrict__ fc1w,
                                                   const float* __restrict__ fc1b,
                                                   const float* __restrict__ fc2w,
                                                   const float* __restrict__ fc2b,
                                                   float* __restrict__ out) {
    __shared__ float sa[32], sc[32];
    int g = threadIdx.x;
    if (g < 32) {
        float mean = stats3[g] * (1.0f / NN);
        float var  = fmaxf(stats3[32 + g] * (1.0f / NN) - mean * mean, 0.f);
        float av = g3[g] * rsqrtf(var + 1e-5f);
        sa[g] = av;
        sc[g] = be3[g] - mean * av;
    }
    __syncthreads();
    if (g >= BB) return;
    float inv = 1.f / fmaxf(pcnt[g], 1.f);
    float xv[32];
#pragma unroll
    for (int c = 0; c < 32; c++) xv[c] = fmaf(sa[c], pooled[g * 32 + c] * inv, sc[c]);
    float u[32];
#pragma unroll 4
    for (int k = 0; k < 32; k++) {
        float s = fc1b[k];
#pragma unroll
        for (int c = 0; c < 32; c++) s = fmaf(xv[c], fc1w[c * 32 + k], s);
        u[k] = fmaxf(s, 0.f);
    }
    float l[8];
#pragma unroll
    for (int o = 0; o < 8; o++) {
        float s = fc2b[o];
#pragma unroll
        for (int k = 0; k < 32; k++) s = fmaf(u[k], fc2w[k * 8 + o], s);
        l[o] = s;
    }
    float m = l[0];
#pragma unroll
    for (int o = 1; o < 8; o++) m = fmaxf(m, l[o]);
    float se = 0.f;
#pragma unroll
    for (int o = 0; o < 8; o++) se += expf(l[o] - m);
    float lse = logf(se) + m;
#pragma unroll
    for (int o = 0; o < 8; o++) out[g * 8 + o] = l[o] - lse;
}

extern "C" void kernel_launch(void* const* d_in, const int* in_sizes, int n_in,
                              void* d_out, int out_size, void* d_ws, size_t ws_size,
                              hipStream_t stream) {
    const float* x    = (const float*)d_in[0];
    const int*   ei   = (const int*)d_in[1];
    const int*   batch= (const int*)d_in[2];
    const float* w1_0 = (const float*)d_in[3];
    const float* b1_0 = (const float*)d_in[4];
    const float* w2_0 = (const float*)d_in[5];
    const float* b2_0 = (const float*)d_in[6];
    const float* g_0  = (const float*)d_in[7];
    const float* be_0 = (const float*)d_in[8];
    const float* w1s  = (const float*)d_in[9];
    const float* b1s  = (const float*)d_in[10];
    const float* w2s  = (const float*)d_in[11];
    const float* b2s  = (const float*)d_in[12];
    const float* gs   = (const float*)d_in[13];
    const float* bes  = (const float*)d_in[14];
    const float* fc1w = (const float*)d_in[15];
    const float* fc1b = (const float*)d_in[16];
    const float* fc2w = (const float*)d_in[17];
    const float* fc2b = (const float*)d_in[18];
    float* out = (float*)d_out;

    char* ws = (char*)d_ws;
    uint4*    q4     = (uint4*)(ws + Q_OFF);
    float*    agg    = (float*)(ws + AGG_OFF);
    float*    h      = (float*)(ws + H_OFF);
    int*      epack  = (int*)(ws + EPACK_OFF);
    int*      srcs   = (int*)(ws + SRC_OFF);
    int*      off    = (int*)(ws + OFF_OFF);
    int*      hist   = (int*)(ws + HIST_OFF);
    int*      start  = (int*)(ws + START_OFF);
    int*      bbase  = (int*)(ws + BBASE_OFF);
    float*    stats  = (float*)(ws + STATS_OFF);   // 4 slots x 64
    float*    pooled = (float*)(ws + POOLED_OFF);
    float*    pcnt   = (float*)(ws + PCNT_OFF);

    (void)hipMemsetAsync(ws + ZERO_OFF, 0, ZERO_BYTES, stream);

    // CSR build chain
    hist_kernel<<<EBLK, 256, 0, stream>>>(ei, hist);
    bucket_scan_kernel<<<1, NBKT, 0, stream>>>(hist, bbase, start);
    scatter_kernel<<<EBLK, 256, 0, stream>>>(ei, start, epack);
    csr_compact_kernel<<<NBKT * 4, 256, 0, stream>>>(epack, bbase, off, srcs);

    const int pblk = (NN + 63) / 64;
    const int mblk = (NN + 63) / 64;
    const int gblk = (NN * 4 + 255) / 256;

    // layer 0 (F_IN=128, no input BN)
    proj_kernel<128><<<pblk, 256, 0, stream>>>(x, w1_0, nullptr, nullptr, nullptr, q4);
    gather_kernel<<<gblk, 256, 0, stream>>>(q4, srcs, off, b1_0, agg);
    mlp_kernel<<<mblk, 64, 0, stream>>>(agg, w2_0, b2_0, h, stats);

    // layers 1..3, prev BN computed in proj from raw stats slot
    for (int i = 0; i < 3; i++) {
        const float* st_prev = stats + i * 64;
        proj_kernel<32><<<pblk, 256, 0, stream>>>(h, w1s + i * 1024, st_prev,
                                                  gs + i * 32, bes + i * 32, q4);
        gather_kernel<<<gblk, 256, 0, stream>>>(q4, srcs, off, b1s + i * 32, agg);
        mlp_kernel<<<mblk, 64, 0, stream>>>(agg, w2s + i * 1024, b2s + i * 32, h,
                                            stats + (i + 1) * 64);
    }

    int pthreads = ((NN + PR - 1) / PR) * 32;
    pool_kernel<<<(pthreads + 255) / 256, 256, 0, stream>>>(h, batch, pooled, pcnt);
    head_kernel<<<1, 128, 0, stream>>>(pooled, pcnt, stats + 3 * 64, gs + 2 * 32,
                                       bes + 2 * 32, fc1w, fc1b, fc2w, fc2b, out);
}

// Round 12
// 721.607 us; speedup vs baseline: 1.1792x; 1.1792x over previous
//
#include <hip/hip_runtime.h>
#include <hip/hip_bf16.h>

#define NN   100000
#define EE   3200000
#define HH   32
#define BB   128
#define KMAX 96
#define LSTRIDE 97       // LDS row stride (96 is 0 mod 32 -> bank storm)
#define NBKT 256         // dst buckets
#define BSPAN 391        // ceil(NN/NBKT)
#define WSPAN 98         // csr-build window (4 windows/bucket)
#define EBLK 256         // edge-chunk blocks
#define CHUNK 12500      // EE / EBLK exactly

// ws layout (bytes), non-overlapping (~60 MB). agg eliminated (mlp fused into gather).
static constexpr size_t Q_OFF      = 0;           // N*32 bf16 = 6.4 MB
static constexpr size_t H_OFF      = 6400000;     // N*32 f32 = 12.8 MB
static constexpr size_t EPACK_OFF  = 19200000;    // EE int = 12.8 MB
static constexpr size_t SRC_OFF    = 32000000;    // EE int dense csr
static constexpr size_t OFF_OFF    = 44800000;    // (N+1) int
static constexpr size_t HIST_OFF   = 45300000;    // EBLK*NBKT int = 256 KB
static constexpr size_t START_OFF  = 45600000;    // EBLK*NBKT int = 256 KB
static constexpr size_t BBASE_OFF  = 45900000;    // (NBKT+1) int
static constexpr size_t STATS_OFF  = 45910000;    // 4 layers x 64 f32
static constexpr size_t POOLED_OFF = 45911024;    // B*32 f32
static constexpr size_t PCNT_OFF   = 45927408;    // B f32
static constexpr size_t ZERO_OFF   = STATS_OFF;
static constexpr size_t ZERO_BYTES = 17920;

// ---- K1: per-block LDS histogram of dst buckets
__global__ __launch_bounds__(256) void hist_kernel(const int* __restrict__ ei,
                                                   int* __restrict__ hist) {
    __shared__ int lh[NBKT];
    int tid = threadIdx.x, blk = blockIdx.x;
    for (int i = tid; i < NBKT; i += 256) lh[i] = 0;
    __syncthreads();
    int e0 = blk * CHUNK;
    for (int e = e0 + tid; e < e0 + CHUNK; e += 256) {
        int d = ei[EE + e];
        atomicAdd(&lh[d / BSPAN], 1);
    }
    __syncthreads();
    for (int i = tid; i < NBKT; i += 256) hist[blk * NBKT + i] = lh[i];
}

// ---- K2 (fused totals+scan+starts): 1 block, thread t owns bucket t
__global__ __launch_bounds__(NBKT) void bucket_scan_kernel(const int* __restrict__ hist,
                                                           int* __restrict__ bbase,
                                                           int* __restrict__ start) {
    __shared__ int sm[NBKT];
    int t = threadIdx.x;
    int mine = 0;
    for (int blk = 0; blk < EBLK; blk++) mine += hist[blk * NBKT + t];
    sm[t] = mine;
    __syncthreads();
    for (int off = 1; off < NBKT; off <<= 1) {
        int v = (t >= off) ? sm[t - off] : 0;
        __syncthreads();
        sm[t] += v;
        __syncthreads();
    }
    int base = sm[t] - mine;   // exclusive
    bbase[t] = base;
    if (t == NBKT - 1) bbase[NBKT] = sm[t];
    int run = base;
    for (int blk = 0; blk < EBLK; blk++) {
        start[blk * NBKT + t] = run;
        run += hist[blk * NBKT + t];
    }
}

// ---- K3: scatter packed (src | dstoff<<17) into bucket-grouped array
__global__ __launch_bounds__(256) void scatter_kernel(const int* __restrict__ ei,
                                                      const int* __restrict__ start,
                                                      int* __restrict__ epack) {
    __shared__ int loff[NBKT];
    int tid = threadIdx.x, blk = blockIdx.x;
    for (int i = tid; i < NBKT; i += 256) loff[i] = start[blk * NBKT + i];
    __syncthreads();
    int e0 = blk * CHUNK;
    for (int e = e0 + tid; e < e0 + CHUNK; e += 256) {
        int s = ei[e];
        int d = ei[EE + e];
        int b = d / BSPAN;
        int slot = atomicAdd(&loff[b], 1);
        epack[slot] = s | ((d - b * BSPAN) << 17);
    }
}

// ---- K4: compact CSR build (r10 form: stride-97 LDS, NO sort — r11's insertion
// sort was O(d^2) serial/divergent and cost +136 us)
__global__ __launch_bounds__(256) void csr_compact_kernel(const int* __restrict__ epack,
                                                          const int* __restrict__ bbase,
                                                          int* __restrict__ off,
                                                          int* __restrict__ srcs) {
    __shared__ int lcnt[WSPAN];
    __shared__ int lbase[WSPAN + 1];
    __shared__ int lcsr[WSPAN * LSTRIDE];   // 98*97*4 = 38024 B
    __shared__ int sh_before;
    int blk = blockIdx.x;
    int b = blk >> 2, w = blk & 3;
    int base = b * BSPAN;
    int span = NN - base;
    if (span <= 0) return;
    if (span > BSPAN) span = BSPAN;
    int wstart = w * WSPAN;
    if (wstart >= span) return;
    int wend = min(wstart + WSPAN, span);
    int wn = wend - wstart;
    int tid = threadIdx.x;
    if (tid == 0) sh_before = 0;
    for (int i = tid; i < wn; i += 256) lcnt[i] = 0;
    __syncthreads();
    int p0 = bbase[b], p1 = bbase[b + 1];
    int nbefore = 0;
    for (int i = p0 + tid; i < p1; i += 256) {
        int wd = epack[i];
        int ld = wd >> 17;
        if (ld < wstart) nbefore++;
        else if (ld < wend) {
            int slot = atomicAdd(&lcnt[ld - wstart], 1);
            if (slot < KMAX) lcsr[(ld - wstart) * LSTRIDE + slot] = wd & 0x1FFFF;
        }
    }
    atomicAdd(&sh_before, nbefore);
    __syncthreads();
    if (tid == 0) {
        int run = 0;
        for (int i = 0; i < wn; i++) { lbase[i] = run; run += min(lcnt[i], KMAX); }
        lbase[wn] = run;
    }
    __syncthreads();
    int w0 = p0 + sh_before;
    for (int i = tid; i < wn; i += 256) off[base + wstart + i] = w0 + lbase[i];
    if (base + wend == NN && tid == 0) off[NN] = w0 + lbase[wn];
    int m = lbase[wn];
    for (int j = tid; j < m; j += 256) {
        int lo = 0, hi = wn - 1;
        while (lo < hi) {
            int mid = (lo + hi + 1) >> 1;
            if (lbase[mid] <= j) lo = mid; else hi = mid - 1;
        }
        srcs[w0 + j] = lcsr[lo * LSTRIDE + (j - lbase[lo])];
    }
}

__device__ __forceinline__ unsigned bf16rn(float f) {
    unsigned b = __float_as_uint(f);
    return (b + 0x7fffu + ((b >> 16) & 1u)) >> 16;   // RNE
}

__device__ __forceinline__ void acc_row(float* a, uint4 v) {
    a[0] += __uint_as_float(v.x << 16);
    a[1] += __uint_as_float(v.x & 0xffff0000u);
    a[2] += __uint_as_float(v.y << 16);
    a[3] += __uint_as_float(v.y & 0xffff0000u);
    a[4] += __uint_as_float(v.z << 16);
    a[5] += __uint_as_float(v.z & 0xffff0000u);
    a[6] += __uint_as_float(v.w << 16);
    a[7] += __uint_as_float(v.w & 0xffff0000u);
}

// ---- projection q(bf16) = BN(h) @ w1, 4-way K-split across waves (r10-proven)
template <int FIN>
__global__ __launch_bounds__(256) void proj_kernel(const float* __restrict__ hin,
                                                   const float* __restrict__ w1,
                                                   const float* __restrict__ stats_prev,
                                                   const float* __restrict__ gamma,
                                                   const float* __restrict__ beta,
                                                   uint4* __restrict__ q4) {
    constexpr int JC = FIN / 4;
    __shared__ float sa[32], sc[32];
    __shared__ float part[4 * 64 * 33];
    int tid = threadIdx.x;
    if constexpr (FIN == 32) {
        if (tid < 32) {
            float mean = stats_prev[tid] * (1.0f / NN);
            float var  = fmaxf(stats_prev[32 + tid] * (1.0f / NN) - mean * mean, 0.f);
            float av = gamma[tid] * rsqrtf(var + 1e-5f);
            sa[tid] = av;
            sc[tid] = beta[tid] - mean * av;
        }
        __syncthreads();
    }
    int wv = __builtin_amdgcn_readfirstlane(tid >> 6);
    int ln = tid & 63;
    int n = blockIdx.x * 64 + ln;
    float acc[32];
#pragma unroll
    for (int c = 0; c < 32; c++) acc[c] = 0.f;
    if (n < NN) {
        const float4* h4 = (const float4*)(hin + (size_t)n * FIN + wv * JC);
        float hv[JC];
#pragma unroll
        for (int k = 0; k < JC / 4; k++) {
            float4 v = h4[k];
            hv[4*k] = v.x; hv[4*k+1] = v.y; hv[4*k+2] = v.z; hv[4*k+3] = v.w;
        }
        if constexpr (FIN == 32) {
#pragma unroll
            for (int j = 0; j < JC; j++) hv[j] = fmaf(hv[j], sa[wv * JC + j], sc[wv * JC + j]);
        }
#pragma unroll 4
        for (int j = 0; j < JC; j++) {
            float hvj = hv[j];
            const float* wrow = w1 + (size_t)(wv * JC + j) * 32;
#pragma unroll
            for (int c = 0; c < 32; c++) acc[c] = fmaf(hvj, wrow[c], acc[c]);
        }
    }
    float* my = part + (wv * 64 + ln) * 33;
#pragma unroll
    for (int c = 0; c < 32; c++) my[c] = acc[c];
    __syncthreads();
    int node = tid >> 2, p = tid & 3;
    int n2 = blockIdx.x * 64 + node;
    if (n2 >= NN) return;
    float r[8];
#pragma unroll
    for (int k = 0; k < 8; k++) {
        int c = p * 8 + k;
        r[k] = (part[(0 * 64 + node) * 33 + c] + part[(1 * 64 + node) * 33 + c])
             + (part[(2 * 64 + node) * 33 + c] + part[(3 * 64 + node) * 33 + c]);
    }
    uint4 u;
    u.x = bf16rn(r[0]) | (bf16rn(r[1]) << 16);
    u.y = bf16rn(r[2]) | (bf16rn(r[3]) << 16);
    u.z = bf16rn(r[4]) | (bf16rn(r[5]) << 16);
    u.w = bf16rn(r[6]) | (bf16rn(r[7]) << 16);
    q4[(size_t)n2 * 4 + p] = u;
}

// ---- fused gather + MLP + BN-stats (gmlp v2).
// Per node (4 lanes): z = q[n] + b1 + sum q[src]  (r10's proven gather core);
// then quad-shuffle assembles relu(z)[32] in-register, each lane computes its
// 8 output channels against transposed stride-33 LDS w2 (conflict-free
// broadcast reads), relu, writes h, LDS-atomic stats; ONE end-of-kernel
// __syncthreads + 64 global atomics. No agg array, no separate mlp dispatch.
__global__ __launch_bounds__(256) void gmlp_kernel(const uint4* __restrict__ q4,
                                                   const int* __restrict__ srcs,
                                                   const int* __restrict__ off,
                                                   const float* __restrict__ b1,
                                                   const float* __restrict__ w2,
                                                   const float* __restrict__ b2,
                                                   float* __restrict__ hout,
                                                   float* __restrict__ stats) {
    __shared__ float w2t[32 * 33];   // [c][j], stride 33 -> bank (c+j)%32
    __shared__ float sacc[64];       // s[32], sq[32]
    int tid = threadIdx.x;
    for (int i = tid; i < 1024; i += 256) w2t[(i & 31) * 33 + (i >> 5)] = w2[i];
    if (tid < 64) sacc[tid] = 0.f;
    __syncthreads();

    int t = blockIdx.x * 256 + tid;
    int n = t >> 2;
    int p = t & 3;
    if (n < NN) {
        float a[8];
#pragma unroll
        for (int k = 0; k < 8; k++) a[k] = b1[p * 8 + k];
        acc_row(a, q4[(size_t)n * 4 + p]);   // self term
        int o0 = off[n];
        int d = off[n + 1] - o0;
        const int* lst = srcs + o0;
        int i = 0;
        for (; i + 8 <= d; i += 8) {
            int s0 = __builtin_nontemporal_load(lst + i);
            int s1 = __builtin_nontemporal_load(lst + i + 1);
            int s2 = __builtin_nontemporal_load(lst + i + 2);
            int s3 = __builtin_nontemporal_load(lst + i + 3);
            int s4 = __builtin_nontemporal_load(lst + i + 4);
            int s5 = __builtin_nontemporal_load(lst + i + 5);
            int s6 = __builtin_nontemporal_load(lst + i + 6);
            int s7 = __builtin_nontemporal_load(lst + i + 7);
            uint4 v0 = q4[(size_t)s0 * 4 + p];
            uint4 v1 = q4[(size_t)s1 * 4 + p];
            uint4 v2 = q4[(size_t)s2 * 4 + p];
            uint4 v3 = q4[(size_t)s3 * 4 + p];
            uint4 v4 = q4[(size_t)s4 * 4 + p];
            uint4 v5 = q4[(size_t)s5 * 4 + p];
            uint4 v6 = q4[(size_t)s6 * 4 + p];
            uint4 v7 = q4[(size_t)s7 * 4 + p];
            acc_row(a, v0); acc_row(a, v1); acc_row(a, v2); acc_row(a, v3);
            acc_row(a, v4); acc_row(a, v5); acc_row(a, v6); acc_row(a, v7);
        }
        for (; i < d; i++) {
            int s = __builtin_nontemporal_load(lst + i);
            acc_row(a, q4[(size_t)s * 4 + p]);
        }
        // ---- epilogue: u = relu(z), quad-exchange to full 32
        float um[8];
#pragma unroll
        for (int k = 0; k < 8; k++) um[k] = fmaxf(a[k], 0.f);
        float u16[16];
        {
            int half = p & 1;
#pragma unroll
            for (int k = 0; k < 8; k++) {
                float o = __shfl_xor(um[k], 1);
                u16[half * 8 + k] = um[k];
                u16[(half ^ 1) * 8 + k] = o;
            }
        }
        float u32v[32];
        {
            int halfq = (p >> 1) & 1;
#pragma unroll
            for (int k = 0; k < 16; k++) {
                float o = __shfl_xor(u16[k], 2);
                u32v[halfq * 16 + k] = u16[k];
                u32v[(halfq ^ 1) * 16 + k] = o;
            }
        }
        // v[k] = b2 + u32 . w2[:, p*8+k]
        float v[8];
#pragma unroll
        for (int k = 0; k < 8; k++) v[k] = b2[p * 8 + k];
#pragma unroll 4
        for (int j = 0; j < 32; j++) {
            float uj = u32v[j];
#pragma unroll
            for (int k = 0; k < 8; k++)
                v[k] = fmaf(uj, w2t[(p * 8 + k) * 33 + j], v[k]);
        }
        float r[8];
#pragma unroll
        for (int k = 0; k < 8; k++) r[k] = fmaxf(v[k], 0.f);
        float4* hr = (float4*)(hout + (size_t)n * 32 + p * 8);
        float4 f0, f1;
        f0.x = r[0]; f0.y = r[1]; f0.z = r[2]; f0.w = r[3];
        f1.x = r[4]; f1.y = r[5]; f1.z = r[6]; f1.w = r[7];
        hr[0] = f0; hr[1] = f1;
#pragma unroll
        for (int k = 0; k < 8; k++) {
            atomicAdd(&sacc[p * 8 + k], r[k]);
            atomicAdd(&sacc[32 + p * 8 + k], r[k] * r[k]);
        }
    }
    __syncthreads();
    if (tid < 64) atomicAdd(&stats[tid], sacc[tid]);
}

// ---- pooling: segment sums of raw h3 (sorted batch -> run-length flush)
#define PR 16
__global__ __launch_bounds__(256) void pool_kernel(const float* __restrict__ h,
                                                   const int* __restrict__ batch,
                                                   float* __restrict__ pooled,
                                                   float* __restrict__ pcnt) {
    int t = blockIdx.x * 256 + threadIdx.x;
    int c = t & 31;
    int g = t >> 5;
    int r0 = g * PR;
    if (r0 >= NN) return;
    int r1 = min(r0 + PR, NN);
    int cur = batch[r0];
    float acc = 0.f, cn = 0.f;
    for (int rr = r0; rr < r1; rr++) {
        int b = batch[rr];
        if (b != cur) {
            atomicAdd(&pooled[cur * 32 + c], acc);
            if (c == 0) atomicAdd(&pcnt[cur], cn);
            acc = 0.f; cn = 0.f; cur = b;
        }
        acc += h[(size_t)rr * 32 + c];
        cn += 1.f;
    }
    atomicAdd(&pooled[cur * 32 + c], acc);
    if (c == 0) atomicAdd(&pcnt[cur], cn);
}

// ---- head: BN3 (from raw stats3) on pooled means, fc1+relu, fc2, log_softmax
__global__ __launch_bounds__(128) void head_kernel(const float* __restrict__ pooled,
                                                   const float* __restrict__ pcnt,
                                                   const float* __restrict__ stats3,
                                                   const float* __restrict__ g3,
                                                   const float* __restrict__ be3,
                                                   const float* __restrict__ fc1w,
                                                   const float* __restrict__ fc1b,
                                                   const float* __restrict__ fc2w,
                                                   const float* __restrict__ fc2b,
                                                   float* __restrict__ out) {
    __shared__ float sa[32], sc[32];
    int g = threadIdx.x;
    if (g < 32) {
        float mean = stats3[g] * (1.0f / NN);
        float var  = fmaxf(stats3[32 + g] * (1.0f / NN) - mean * mean, 0.f);
        float av = g3[g] * rsqrtf(var + 1e-5f);
        sa[g] = av;
        sc[g] = be3[g] - mean * av;
    }
    __syncthreads();
    if (g >= BB) return;
    float inv = 1.f / fmaxf(pcnt[g], 1.f);
    float xv[32];
#pragma unroll
    for (int c = 0; c < 32; c++) xv[c] = fmaf(sa[c], pooled[g * 32 + c] * inv, sc[c]);
    float u[32];
#pragma unroll 4
    for (int k = 0; k < 32; k++) {
        float s = fc1b[k];
#pragma unroll
        for (int c = 0; c < 32; c++) s = fmaf(xv[c], fc1w[c * 32 + k], s);
        u[k] = fmaxf(s, 0.f);
    }
    float l[8];
#pragma unroll
    for (int o = 0; o < 8; o++) {
        float s = fc2b[o];
#pragma unroll
        for (int k = 0; k < 32; k++) s = fmaf(u[k], fc2w[k * 8 + o], s);
        l[o] = s;
    }
    float m = l[0];
#pragma unroll
    for (int o = 1; o < 8; o++) m = fmaxf(m, l[o]);
    float se = 0.f;
#pragma unroll
    for (int o = 0; o < 8; o++) se += expf(l[o] - m);
    float lse = logf(se) + m;
#pragma unroll
    for (int o = 0; o < 8; o++) out[g * 8 + o] = l[o] - lse;
}

extern "C" void kernel_launch(void* const* d_in, const int* in_sizes, int n_in,
                              void* d_out, int out_size, void* d_ws, size_t ws_size,
                              hipStream_t stream) {
    const float* x    = (const float*)d_in[0];
    const int*   ei   = (const int*)d_in[1];
    const int*   batch= (const int*)d_in[2];
    const float* w1_0 = (const float*)d_in[3];
    const float* b1_0 = (const float*)d_in[4];
    const float* w2_0 = (const float*)d_in[5];
    const float* b2_0 = (const float*)d_in[6];
    const float* g_0  = (const float*)d_in[7];
    const float* be_0 = (const float*)d_in[8];
    const float* w1s  = (const float*)d_in[9];
    const float* b1s  = (const float*)d_in[10];
    const float* w2s  = (const float*)d_in[11];
    const float* b2s  = (const float*)d_in[12];
    const float* gs   = (const float*)d_in[13];
    const float* bes  = (const float*)d_in[14];
    const float* fc1w = (const float*)d_in[15];
    const float* fc1b = (const float*)d_in[16];
    const float* fc2w = (const float*)d_in[17];
    const float* fc2b = (const float*)d_in[18];
    float* out = (float*)d_out;

    char* ws = (char*)d_ws;
    uint4*    q4     = (uint4*)(ws + Q_OFF);
    float*    h      = (float*)(ws + H_OFF);
    int*      epack  = (int*)(ws + EPACK_OFF);
    int*      srcs   = (int*)(ws + SRC_OFF);
    int*      off    = (int*)(ws + OFF_OFF);
    int*      hist   = (int*)(ws + HIST_OFF);
    int*      start  = (int*)(ws + START_OFF);
    int*      bbase  = (int*)(ws + BBASE_OFF);
    float*    stats  = (float*)(ws + STATS_OFF);   // 4 slots x 64
    float*    pooled = (float*)(ws + POOLED_OFF);
    float*    pcnt   = (float*)(ws + PCNT_OFF);

    (void)hipMemsetAsync(ws + ZERO_OFF, 0, ZERO_BYTES, stream);

    // CSR build chain
    hist_kernel<<<EBLK, 256, 0, stream>>>(ei, hist);
    bucket_scan_kernel<<<1, NBKT, 0, stream>>>(hist, bbase, start);
    scatter_kernel<<<EBLK, 256, 0, stream>>>(ei, start, epack);
    csr_compact_kernel<<<NBKT * 4, 256, 0, stream>>>(epack, bbase, off, srcs);

    const int pblk = (NN + 63) / 64;
    const int gblk = (NN * 4 + 255) / 256;

    // layer 0 (F_IN=128, no input BN)
    proj_kernel<128><<<pblk, 256, 0, stream>>>(x, w1_0, nullptr, nullptr, nullptr, q4);
    gmlp_kernel<<<gblk, 256, 0, stream>>>(q4, srcs, off, b1_0, w2_0, b2_0, h, stats);

    // layers 1..3, prev BN computed in proj from raw stats slot
    for (int i = 0; i < 3; i++) {
        const float* st_prev = stats + i * 64;
        proj_kernel<32><<<pblk, 256, 0, stream>>>(h, w1s + i * 1024, st_prev,
                                                  gs + i * 32, bes + i * 32, q4);
        gmlp_kernel<<<gblk, 256, 0, stream>>>(q4, srcs, off, b1s + i * 32,
                                              w2s + i * 1024, b2s + i * 32, h,
                                              stats + (i + 1) * 64);
    }

    int pthreads = ((NN + PR - 1) / PR) * 32;
    pool_kernel<<<(pthreads + 255) / 256, 256, 0, stream>>>(h, batch, pooled, pcnt);
    head_kernel<<<1, 128, 0, stream>>>(pooled, pcnt, stats + 3 * 64, gs + 2 * 32,
                                       bes + 2 * 32, fc1w, fc1b, fc2w, fc2b, out);
}

// Round 13
// 594.956 us; speedup vs baseline: 1.4302x; 1.2129x over previous
//
#include <hip/hip_runtime.h>
#include <hip/hip_bf16.h>

#define NN   100000
#define EE   3200000
#define HH   32
#define BB   128
#define KMAX 96
#define LSTRIDE 97       // LDS row stride (96 is 0 mod 32 -> bank storm)
#define NBKT 256         // dst buckets
#define BSPAN 391        // ceil(NN/NBKT)
#define WSPAN 98         // csr-build window (4 windows/bucket)
#define QS   25000       // src quartile span
#define EBLK 256         // edge-chunk blocks
#define CHUNK 12500      // EE / EBLK exactly

// ws layout (bytes), non-overlapping (~72 MB)
static constexpr size_t Q_OFF      = 0;           // N*32 bf16 = 6.4 MB
static constexpr size_t AGG_OFF    = 6400000;     // N*32 f32 = 12.8 MB
static constexpr size_t H_OFF      = 19200000;    // N*32 f32 = 12.8 MB
static constexpr size_t EPACK_OFF  = 32000000;    // EE int = 12.8 MB (stage-1)
static constexpr size_t EPACK2_OFF = 44800000;    // EE int = 12.8 MB (stage-2 regrouped)
static constexpr size_t SRC_OFF    = 57600000;    // EE int dense csr
static constexpr size_t OFF_OFF    = 70400000;    // (N+1) int
static constexpr size_t HIST_OFF   = 70900000;    // EBLK*NBKT int = 256 KB
static constexpr size_t START_OFF  = 71200000;    // EBLK*NBKT int = 256 KB
static constexpr size_t BBASE_OFF  = 71500000;    // (NBKT+1) int
static constexpr size_t KB2_OFF    = 71510000;    // NBKT*17 int = 17.4 KB
static constexpr size_t STATS_OFF  = 71530000;    // 4 layers x 64 f32
static constexpr size_t POOLED_OFF = 71531024;    // B*32 f32
static constexpr size_t PCNT_OFF   = 71547408;    // B f32
static constexpr size_t ZERO_OFF   = STATS_OFF;
static constexpr size_t ZERO_BYTES = 17920;

// ---- K1: per-block LDS histogram of dst buckets
__global__ __launch_bounds__(256) void hist_kernel(const int* __restrict__ ei,
                                                   int* __restrict__ hist) {
    __shared__ int lh[NBKT];
    int tid = threadIdx.x, blk = blockIdx.x;
    for (int i = tid; i < NBKT; i += 256) lh[i] = 0;
    __syncthreads();
    int e0 = blk * CHUNK;
    for (int e = e0 + tid; e < e0 + CHUNK; e += 256) {
        int d = ei[EE + e];
        atomicAdd(&lh[d / BSPAN], 1);
    }
    __syncthreads();
    for (int i = tid; i < NBKT; i += 256) hist[blk * NBKT + i] = lh[i];
}

// ---- K2 (fused totals+scan+starts): 1 block, thread t owns bucket t
__global__ __launch_bounds__(NBKT) void bucket_scan_kernel(const int* __restrict__ hist,
                                                           int* __restrict__ bbase,
                                                           int* __restrict__ start) {
    __shared__ int sm[NBKT];
    int t = threadIdx.x;
    int mine = 0;
    for (int blk = 0; blk < EBLK; blk++) mine += hist[blk * NBKT + t];
    sm[t] = mine;
    __syncthreads();
    for (int off = 1; off < NBKT; off <<= 1) {
        int v = (t >= off) ? sm[t - off] : 0;
        __syncthreads();
        sm[t] += v;
        __syncthreads();
    }
    int base = sm[t] - mine;   // exclusive
    bbase[t] = base;
    if (t == NBKT - 1) bbase[NBKT] = sm[t];
    int run = base;
    for (int blk = 0; blk < EBLK; blk++) {
        start[blk * NBKT + t] = run;
        run += hist[blk * NBKT + t];
    }
}

// ---- K3: scatter packed (src | dstoff<<17) into bucket-grouped array (stage 1)
__global__ __launch_bounds__(256) void scatter_kernel(const int* __restrict__ ei,
                                                      const int* __restrict__ start,
                                                      int* __restrict__ epack) {
    __shared__ int loff[NBKT];
    int tid = threadIdx.x, blk = blockIdx.x;
    for (int i = tid; i < NBKT; i += 256) loff[i] = start[blk * NBKT + i];
    __syncthreads();
    int e0 = blk * CHUNK;
    for (int e = e0 + tid; e < e0 + CHUNK; e += 256) {
        int s = ei[e];
        int d = ei[EE + e];
        int b = d / BSPAN;
        int slot = atomicAdd(&loff[b], 1);
        epack[slot] = s | ((d - b * BSPAN) << 17);
    }
}

// ---- K3b: stage-2 rescatter. One block per dst-bucket; regroup its edges by
// (window, src-quartile) = 16 keys -> ~780-edge dense runs (no write amp).
// Result: per-node neighbor lists come out approx src-quartile-sorted for free,
// turning the gather's random reads into a ~2-3 MB moving src window (L2-fit).
__global__ __launch_bounds__(256) void rescatter_kernel(const int* __restrict__ epack,
                                                        const int* __restrict__ bbase,
                                                        int* __restrict__ epack2,
                                                        int* __restrict__ kb2) {
    __shared__ int lh[16];
    __shared__ int lofs[17];
    __shared__ int lrun[16];
    int b = blockIdx.x, tid = threadIdx.x;
    if (tid < 16) lh[tid] = 0;
    __syncthreads();
    int p0 = bbase[b], p1 = bbase[b + 1];
    for (int i = p0 + tid; i < p1; i += 256) {
        int wd = epack[i];
        int key = ((wd >> 17) / WSPAN) * 4 + (wd & 0x1FFFF) / QS;
        atomicAdd(&lh[key], 1);
    }
    __syncthreads();
    if (tid == 0) {
        int run = p0;
        for (int k = 0; k < 16; k++) { lofs[k] = run; run += lh[k]; }
        lofs[16] = run;
    }
    __syncthreads();
    if (tid < 17) kb2[b * 17 + tid] = lofs[tid];
    if (tid < 16) lrun[tid] = lofs[tid];
    __syncthreads();
    for (int i = p0 + tid; i < p1; i += 256) {
        int wd = epack[i];
        int key = ((wd >> 17) / WSPAN) * 4 + (wd & 0x1FFFF) / QS;
        int slot = atomicAdd(&lrun[key], 1);
        epack2[slot] = wd;
    }
}

// ---- K4: compact CSR build. Each (bucket,window) block scans ONLY its window's
// range [kb2[w*4], kb2[w*4+4]) (4x less scan than r10, no before-count); appends
// arrive src-quartile-grouped -> node lists approx sorted by src quartile.
__global__ __launch_bounds__(256) void csr_compact_kernel(const int* __restrict__ epack2,
                                                          const int* __restrict__ kb2,
                                                          int* __restrict__ off,
                                                          int* __restrict__ srcs) {
    __shared__ int lcnt[WSPAN];
    __shared__ int lbase[WSPAN + 1];
    __shared__ int lcsr[WSPAN * LSTRIDE];   // 98*97*4 = 38024 B
    int blk = blockIdx.x;
    int b = blk >> 2, w = blk & 3;
    int base = b * BSPAN;
    int span = NN - base;
    if (span <= 0) return;
    if (span > BSPAN) span = BSPAN;
    int wstart = w * WSPAN;
    if (wstart >= span) return;
    int wend = min(wstart + WSPAN, span);
    int wn = wend - wstart;
    int tid = threadIdx.x;
    for (int i = tid; i < wn; i += 256) lcnt[i] = 0;
    __syncthreads();
    int p0w = kb2[b * 17 + w * 4], p1w = kb2[b * 17 + w * 4 + 4];
    for (int i = p0w + tid; i < p1w; i += 256) {
        int wd = epack2[i];
        int ld = (wd >> 17) - wstart;      // guaranteed in [0, wn)
        int slot = atomicAdd(&lcnt[ld], 1);
        if (slot < KMAX) lcsr[ld * LSTRIDE + slot] = wd & 0x1FFFF;
    }
    __syncthreads();
    if (tid == 0) {
        int run = 0;
        for (int i = 0; i < wn; i++) { lbase[i] = run; run += min(lcnt[i], KMAX); }
        lbase[wn] = run;
    }
    __syncthreads();
    for (int i = tid; i < wn; i += 256) off[base + wstart + i] = p0w + lbase[i];
    if (base + wend == NN && tid == 0) off[NN] = p0w + lbase[wn];
    int m = lbase[wn];
    for (int j = tid; j < m; j += 256) {
        int lo = 0, hi = wn - 1;
        while (lo < hi) {
            int mid = (lo + hi + 1) >> 1;
            if (lbase[mid] <= j) lo = mid; else hi = mid - 1;
        }
        srcs[p0w + j] = lcsr[lo * LSTRIDE + (j - lbase[lo])];
    }
}

__device__ __forceinline__ unsigned bf16rn(float f) {
    unsigned b = __float_as_uint(f);
    return (b + 0x7fffu + ((b >> 16) & 1u)) >> 16;   // RNE
}

__device__ __forceinline__ void acc_row(float* a, uint4 v) {
    a[0] += __uint_as_float(v.x << 16);
    a[1] += __uint_as_float(v.x & 0xffff0000u);
    a[2] += __uint_as_float(v.y << 16);
    a[3] += __uint_as_float(v.y & 0xffff0000u);
    a[4] += __uint_as_float(v.z << 16);
    a[5] += __uint_as_float(v.z & 0xffff0000u);
    a[6] += __uint_as_float(v.w << 16);
    a[7] += __uint_as_float(v.w & 0xffff0000u);
}

// ---- projection q(bf16) = BN(h) @ w1, 4-way K-split across waves (r10-proven)
template <int FIN>
__global__ __launch_bounds__(256) void proj_kernel(const float* __restrict__ hin,
                                                   const float* __restrict__ w1,
                                                   const float* __restrict__ stats_prev,
                                                   const float* __restrict__ gamma,
                                                   const float* __restrict__ beta,
                                                   uint4* __restrict__ q4) {
    constexpr int JC = FIN / 4;
    __shared__ float sa[32], sc[32];
    __shared__ float part[4 * 64 * 33];
    int tid = threadIdx.x;
    if constexpr (FIN == 32) {
        if (tid < 32) {
            float mean = stats_prev[tid] * (1.0f / NN);
            float var  = fmaxf(stats_prev[32 + tid] * (1.0f / NN) - mean * mean, 0.f);
            float av = gamma[tid] * rsqrtf(var + 1e-5f);
            sa[tid] = av;
            sc[tid] = beta[tid] - mean * av;
        }
        __syncthreads();
    }
    int wv = __builtin_amdgcn_readfirstlane(tid >> 6);
    int ln = tid & 63;
    int n = blockIdx.x * 64 + ln;
    float acc[32];
#pragma unroll
    for (int c = 0; c < 32; c++) acc[c] = 0.f;
    if (n < NN) {
        const float4* h4 = (const float4*)(hin + (size_t)n * FIN + wv * JC);
        float hv[JC];
#pragma unroll
        for (int k = 0; k < JC / 4; k++) {
            float4 v = h4[k];
            hv[4*k] = v.x; hv[4*k+1] = v.y; hv[4*k+2] = v.z; hv[4*k+3] = v.w;
        }
        if constexpr (FIN == 32) {
#pragma unroll
            for (int j = 0; j < JC; j++) hv[j] = fmaf(hv[j], sa[wv * JC + j], sc[wv * JC + j]);
        }
#pragma unroll 4
        for (int j = 0; j < JC; j++) {
            float hvj = hv[j];
            const float* wrow = w1 + (size_t)(wv * JC + j) * 32;
#pragma unroll
            for (int c = 0; c < 32; c++) acc[c] = fmaf(hvj, wrow[c], acc[c]);
        }
    }
    float* my = part + (wv * 64 + ln) * 33;
#pragma unroll
    for (int c = 0; c < 32; c++) my[c] = acc[c];
    __syncthreads();
    int node = tid >> 2, p = tid & 3;
    int n2 = blockIdx.x * 64 + node;
    if (n2 >= NN) return;
    float r[8];
#pragma unroll
    for (int k = 0; k < 8; k++) {
        int c = p * 8 + k;
        r[k] = (part[(0 * 64 + node) * 33 + c] + part[(1 * 64 + node) * 33 + c])
             + (part[(2 * 64 + node) * 33 + c] + part[(3 * 64 + node) * 33 + c]);
    }
    uint4 u;
    u.x = bf16rn(r[0]) | (bf16rn(r[1]) << 16);
    u.y = bf16rn(r[2]) | (bf16rn(r[3]) << 16);
    u.z = bf16rn(r[4]) | (bf16rn(r[5]) << 16);
    u.w = bf16rn(r[6]) | (bf16rn(r[7]) << 16);
    q4[(size_t)n2 * 4 + p] = u;
}

// ---- gather: agg[n] = q[n] + b1 + sum q[src]. 4 lanes/node x 16 B, 8-unrolled.
// (UNCHANGED from r10 — fusion/splitting attempts all regressed; locality now
// comes from the quartile-ordered srcs lists.)
__global__ __launch_bounds__(256) void gather_kernel(const uint4* __restrict__ q4,
                                                     const int* __restrict__ srcs,
                                                     const int* __restrict__ off,
                                                     const float* __restrict__ b1,
                                                     float* __restrict__ agg) {
    int t = blockIdx.x * 256 + threadIdx.x;
    int n = t >> 2;
    if (n >= NN) return;
    int p = t & 3;
    float a[8];
#pragma unroll
    for (int k = 0; k < 8; k++) a[k] = b1[p * 8 + k];
    acc_row(a, q4[(size_t)n * 4 + p]);   // self term
    int o0 = off[n];
    int d = off[n + 1] - o0;
    const int* lst = srcs + o0;
    int i = 0;
    for (; i + 8 <= d; i += 8) {
        int s0 = __builtin_nontemporal_load(lst + i);
        int s1 = __builtin_nontemporal_load(lst + i + 1);
        int s2 = __builtin_nontemporal_load(lst + i + 2);
        int s3 = __builtin_nontemporal_load(lst + i + 3);
        int s4 = __builtin_nontemporal_load(lst + i + 4);
        int s5 = __builtin_nontemporal_load(lst + i + 5);
        int s6 = __builtin_nontemporal_load(lst + i + 6);
        int s7 = __builtin_nontemporal_load(lst + i + 7);
        uint4 v0 = q4[(size_t)s0 * 4 + p];
        uint4 v1 = q4[(size_t)s1 * 4 + p];
        uint4 v2 = q4[(size_t)s2 * 4 + p];
        uint4 v3 = q4[(size_t)s3 * 4 + p];
        uint4 v4 = q4[(size_t)s4 * 4 + p];
        uint4 v5 = q4[(size_t)s5 * 4 + p];
        uint4 v6 = q4[(size_t)s6 * 4 + p];
        uint4 v7 = q4[(size_t)s7 * 4 + p];
        acc_row(a, v0); acc_row(a, v1); acc_row(a, v2); acc_row(a, v3);
        acc_row(a, v4); acc_row(a, v5); acc_row(a, v6); acc_row(a, v7);
    }
    for (; i < d; i++) {
        int s = __builtin_nontemporal_load(lst + i);
        acc_row(a, q4[(size_t)s * 4 + p]);
    }
    float4* ar = (float4*)(agg + (size_t)n * 32 + p * 8);
    float4 f0, f1;
    f0.x = a[0]; f0.y = a[1]; f0.z = a[2]; f0.w = a[3];
    f1.x = a[4]; f1.y = a[5]; f1.z = a[6]; f1.w = a[7];
    ar[0] = f0; ar[1] = f1;
}

// ---- MLP tail (r10 256-thread form): h = relu(relu(agg)@w2 + b2); BN stats.
__global__ __launch_bounds__(256) void mlp_kernel(const float* __restrict__ agg,
                                                  const float* __restrict__ w2,
                                                  const float* __restrict__ b2,
                                                  float* __restrict__ r,
                                                  float* __restrict__ stats) {
    __shared__ float tile[256 * 33];
    __shared__ float ps[8 * 32];
    __shared__ float pq[8 * 32];
    int tid = threadIdx.x;
    int n = blockIdx.x * 256 + tid;
    float rc[32];
    if (n < NN) {
        float u[32];
        const float4* a4 = (const float4*)(agg + (size_t)n * 32);
#pragma unroll
        for (int k = 0; k < 8; k++) {
            float4 v = a4[k];
            u[4*k]   = fmaxf(v.x, 0.f);
            u[4*k+1] = fmaxf(v.y, 0.f);
            u[4*k+2] = fmaxf(v.z, 0.f);
            u[4*k+3] = fmaxf(v.w, 0.f);
        }
#pragma unroll
        for (int c = 0; c < 32; c++) rc[c] = b2[c];
#pragma unroll 4
        for (int j = 0; j < 32; j++) {
            float uj = u[j];
            const float* wrow = w2 + (size_t)j * 32;
#pragma unroll
            for (int c = 0; c < 32; c++) rc[c] = fmaf(uj, wrow[c], rc[c]);
        }
#pragma unroll
        for (int c = 0; c < 32; c++) rc[c] = fmaxf(rc[c], 0.f);
        float4* rr = (float4*)(r + (size_t)n * 32);
#pragma unroll
        for (int k = 0; k < 8; k++) {
            float4 v; v.x = rc[4*k]; v.y = rc[4*k+1]; v.z = rc[4*k+2]; v.w = rc[4*k+3];
            rr[k] = v;
        }
    } else {
#pragma unroll
        for (int c = 0; c < 32; c++) rc[c] = 0.f;
    }
#pragma unroll
    for (int c = 0; c < 32; c++) tile[tid * 33 + c] = rc[c];
    __syncthreads();
    {
        int c = tid & 31, rb = tid >> 5;
        float s = 0.f, sq = 0.f;
        for (int it = 0; it < 32; it++) {
            float v = tile[(rb * 32 + it) * 33 + c];
            s += v; sq += v * v;
        }
        ps[rb * 32 + c] = s; pq[rb * 32 + c] = sq;
    }
    __syncthreads();
    if (tid < 32) {
        float s = 0.f, sq = 0.f;
#pragma unroll
        for (int rb = 0; rb < 8; rb++) { s += ps[rb * 32 + tid]; sq += pq[rb * 32 + tid]; }
        atomicAdd(&stats[tid], s);
        atomicAdd(&stats[32 + tid], sq);
    }
}

// ---- pooling: segment sums of raw h3 (sorted batch -> run-length flush)
#define PR 16
__global__ __launch_bounds__(256) void pool_kernel(const float* __restrict__ h,
                                                   const int* __restrict__ batch,
                                                   float* __restrict__ pooled,
                                                   float* __restrict__ pcnt) {
    int t = blockIdx.x * 256 + threadIdx.x;
    int c = t & 31;
    int g = t >> 5;
    int r0 = g * PR;
    if (r0 >= NN) return;
    int r1 = min(r0 + PR, NN);
    int cur = batch[r0];
    float acc = 0.f, cn = 0.f;
    for (int rr = r0; rr < r1; rr++) {
        int b = batch[rr];
        if (b != cur) {
            atomicAdd(&pooled[cur * 32 + c], acc);
            if (c == 0) atomicAdd(&pcnt[cur], cn);
            acc = 0.f; cn = 0.f; cur = b;
        }
        acc += h[(size_t)rr * 32 + c];
        cn += 1.f;
    }
    atomicAdd(&pooled[cur * 32 + c], acc);
    if (c == 0) atomicAdd(&pcnt[cur], cn);
}

// ---- head: BN3 (from raw stats3) on pooled means, fc1+relu, fc2, log_softmax
__global__ __launch_bounds__(128) void head_kernel(const float* __restrict__ pooled,
                                                   const float* __restrict__ pcnt,
                                                   const float* __restrict__ stats3,
                                                   const float* __restrict__ g3,
                                                   const float* __restrict__ be3,
                                                   const float* __restrict__ fc1w,
                                                   const float* __restrict__ fc1b,
                                                   const float* __restrict__ fc2w,
                                                   const float* __restrict__ fc2b,
                                                   float* __restrict__ out) {
    __shared__ float sa[32], sc[32];
    int g = threadIdx.x;
    if (g < 32) {
        float mean = stats3[g] * (1.0f / NN);
        float var  = fmaxf(stats3[32 + g] * (1.0f / NN) - mean * mean, 0.f);
        float av = g3[g] * rsqrtf(var + 1e-5f);
        sa[g] = av;
        sc[g] = be3[g] - mean * av;
    }
    __syncthreads();
    if (g >= BB) return;
    float inv = 1.f / fmaxf(pcnt[g], 1.f);
    float xv[32];
#pragma unroll
    for (int c = 0; c < 32; c++) xv[c] = fmaf(sa[c], pooled[g * 32 + c] * inv, sc[c]);
    float u[32];
#pragma unroll 4
    for (int k = 0; k < 32; k++) {
        float s = fc1b[k];
#pragma unroll
        for (int c = 0; c < 32; c++) s = fmaf(xv[c], fc1w[c * 32 + k], s);
        u[k] = fmaxf(s, 0.f);
    }
    float l[8];
#pragma unroll
    for (int o = 0; o < 8; o++) {
        float s = fc2b[o];
#pragma unroll
        for (int k = 0; k < 32; k++) s = fmaf(u[k], fc2w[k * 8 + o], s);
        l[o] = s;
    }
    float m = l[0];
#pragma unroll
    for (int o = 1; o < 8; o++) m = fmaxf(m, l[o]);
    float se = 0.f;
#pragma unroll
    for (int o = 0; o < 8; o++) se += expf(l[o] - m);
    float lse = logf(se) + m;
#pragma unroll
    for (int o = 0; o < 8; o++) out[g * 8 + o] = l[o] - lse;
}

extern "C" void kernel_launch(void* const* d_in, const int* in_sizes, int n_in,
                              void* d_out, int out_size, void* d_ws, size_t ws_size,
                              hipStream_t stream) {
    const float* x    = (const float*)d_in[0];
    const int*   ei   = (const int*)d_in[1];
    const int*   batch= (const int*)d_in[2];
    const float* w1_0 = (const float*)d_in[3];
    const float* b1_0 = (const float*)d_in[4];
    const float* w2_0 = (const float*)d_in[5];
    const float* b2_0 = (const float*)d_in[6];
    const float* g_0  = (const float*)d_in[7];
    const float* be_0 = (const float*)d_in[8];
    const float* w1s  = (const float*)d_in[9];
    const float* b1s  = (const float*)d_in[10];
    const float* w2s  = (const float*)d_in[11];
    const float* b2s  = (const float*)d_in[12];
    const float* gs   = (const float*)d_in[13];
    const float* bes  = (const float*)d_in[14];
    const float* fc1w = (const float*)d_in[15];
    const float* fc1b = (const float*)d_in[16];
    const float* fc2w = (const float*)d_in[17];
    const float* fc2b = (const float*)d_in[18];
    float* out = (float*)d_out;

    char* ws = (char*)d_ws;
    uint4*    q4     = (uint4*)(ws + Q_OFF);
    float*    agg    = (float*)(ws + AGG_OFF);
    float*    h      = (float*)(ws + H_OFF);
    int*      epack  = (int*)(ws + EPACK_OFF);
    int*      epack2 = (int*)(ws + EPACK2_OFF);
    int*      srcs   = (int*)(ws + SRC_OFF);
    int*      off    = (int*)(ws + OFF_OFF);
    int*      hist   = (int*)(ws + HIST_OFF);
    int*      start  = (int*)(ws + START_OFF);
    int*      bbase  = (int*)(ws + BBASE_OFF);
    int*      kb2    = (int*)(ws + KB2_OFF);
    float*    stats  = (float*)(ws + STATS_OFF);   // 4 slots x 64
    float*    pooled = (float*)(ws + POOLED_OFF);
    float*    pcnt   = (float*)(ws + PCNT_OFF);

    (void)hipMemsetAsync(ws + ZERO_OFF, 0, ZERO_BYTES, stream);

    // CSR build chain (stage-1 bucket scatter + stage-2 quartile regroup)
    hist_kernel<<<EBLK, 256, 0, stream>>>(ei, hist);
    bucket_scan_kernel<<<1, NBKT, 0, stream>>>(hist, bbase, start);
    scatter_kernel<<<EBLK, 256, 0, stream>>>(ei, start, epack);
    rescatter_kernel<<<NBKT, 256, 0, stream>>>(epack, bbase, epack2, kb2);
    csr_compact_kernel<<<NBKT * 4, 256, 0, stream>>>(epack2, kb2, off, srcs);

    const int pblk = (NN + 63) / 64;
    const int nblk = (NN + 255) / 256;
    const int gblk = (NN * 4 + 255) / 256;

    // layer 0 (F_IN=128, no input BN)
    proj_kernel<128><<<pblk, 256, 0, stream>>>(x, w1_0, nullptr, nullptr, nullptr, q4);
    gather_kernel<<<gblk, 256, 0, stream>>>(q4, srcs, off, b1_0, agg);
    mlp_kernel<<<nblk, 256, 0, stream>>>(agg, w2_0, b2_0, h, stats);

    // layers 1..3, prev BN computed in proj from raw stats slot
    for (int i = 0; i < 3; i++) {
        const float* st_prev = stats + i * 64;
        proj_kernel<32><<<pblk, 256, 0, stream>>>(h, w1s + i * 1024, st_prev,
                                                  gs + i * 32, bes + i * 32, q4);
        gather_kernel<<<gblk, 256, 0, stream>>>(q4, srcs, off, b1s + i * 32, agg);
        mlp_kernel<<<nblk, 256, 0, stream>>>(agg, w2s + i * 1024, b2s + i * 32, h,
                                             stats + (i + 1) * 64);
    }

    int pthreads = ((NN + PR - 1) / PR) * 32;
    pool_kernel<<<(pthreads + 255) / 256, 256, 0, stream>>>(h, batch, pooled, pcnt);
    head_kernel<<<1, 128, 0, stream>>>(pooled, pcnt, stats + 3 * 64, gs + 2 * 32,
                                       bes + 2 * 32, fc1w, fc1b, fc2w, fc2b, out);
}